// Round 1
// baseline (309.976 us; speedup 1.0000x reference)
//
#include <hip/hip_runtime.h>
#include <hip/hip_bf16.h>
#include <cstdint>

#define D_MODEL 1024
#define NHEADS 16
#define HDIM 64
#define SEQ 2048
#define NBATCH 2
#define BT (NBATCH * SEQ) /* 4096 */

typedef short bf16x8 __attribute__((ext_vector_type(8)));
typedef float f32x4 __attribute__((ext_vector_type(4)));
typedef unsigned short u16;

__device__ inline u16 f2bf(float f) {
    union { float f; unsigned int u; } x;
    x.f = f;
    unsigned int r = (x.u + 0x7fffu + ((x.u >> 16) & 1u)) >> 16;
    return (u16)r;
}

// ---------------- cast kernels ----------------
__global__ void cast_x_kernel(const float* __restrict__ src, u16* __restrict__ dst, int n4) {
    int i = blockIdx.x * blockDim.x + threadIdx.x;
    if (i >= n4) return;
    float4 v = ((const float4*)src)[i];
    ushort4 o;
    o.x = f2bf(v.x); o.y = f2bf(v.y); o.z = f2bf(v.z); o.w = f2bf(v.w);
    ((ushort4*)dst)[i] = o;
}

__global__ void cast_w_kernel(const float* __restrict__ wq, const float* __restrict__ wk,
                              const float* __restrict__ wv, const float* __restrict__ wo,
                              u16* __restrict__ dq, u16* __restrict__ dk,
                              u16* __restrict__ dv, u16* __restrict__ dow) {
    int z = blockIdx.z;
    const float* s = (z == 0) ? wq : (z == 1) ? wk : (z == 2) ? wv : wo;
    u16* d = (z == 0) ? dq : (z == 1) ? dk : (z == 2) ? dv : dow;
    int i = blockIdx.x * blockDim.x + threadIdx.x;
    float4 v = ((const float4*)s)[i];
    ushort4 o;
    o.x = f2bf(v.x); o.y = f2bf(v.y); o.z = f2bf(v.z); o.w = f2bf(v.w);
    ((ushort4*)d)[i] = o;
}

// ---------------- rope tables ----------------
__global__ void rope_table_kernel(float* __restrict__ cosT, float* __restrict__ sinT) {
    int t = blockIdx.x;
    int d = threadIdx.x; // 0..63
    // inv_freq = 10000^(-(d&31)/32)
    float invf = expf(-(float)(d & 31) * (9.210340371976184f / 32.0f));
    float ang = (float)t * invf;
    float s, c;
    sincosf(ang, &s, &c);
    cosT[t * HDIM + d] = c;
    sinT[t * HDIM + d] = s;
}

// ---------------- shared GEMM core: C[128x128] tile, A[M,K] bf16 row-major, Bw[N,K] bf16 row-major ----
__device__ inline void gemm_tile_core(const u16* __restrict__ A, const u16* __restrict__ Bw,
                                      int blkM, int blkN,
                                      u16* Asmem, u16* Bsmem, f32x4 acc[4][4]) {
    const int tid = threadIdx.x;
    const int wave = tid >> 6, lane = tid & 63;
    const int waveM = wave >> 1, waveN = wave & 1;
    const int quad = lane >> 4, l16 = lane & 15;
    const int lr = tid >> 2, lc = (tid & 3) * 8;

    for (int k0 = 0; k0 < D_MODEL; k0 += 32) {
        __syncthreads();
        *(int4*)&Asmem[lr * 32 + lc] = *(const int4*)&A[(blkM * 128 + lr) * D_MODEL + k0 + lc];
        *(int4*)&Asmem[(lr + 64) * 32 + lc] = *(const int4*)&A[(blkM * 128 + lr + 64) * D_MODEL + k0 + lc];
        *(int4*)&Bsmem[lr * 32 + lc] = *(const int4*)&Bw[(blkN * 128 + lr) * D_MODEL + k0 + lc];
        *(int4*)&Bsmem[(lr + 64) * 32 + lc] = *(const int4*)&Bw[(blkN * 128 + lr + 64) * D_MODEL + k0 + lc];
        __syncthreads();
        bf16x8 af[4], bfr[4];
#pragma unroll
        for (int mt = 0; mt < 4; ++mt)
            af[mt] = *(const bf16x8*)&Asmem[(waveM * 64 + mt * 16 + l16) * 32 + quad * 8];
#pragma unroll
        for (int nt = 0; nt < 4; ++nt)
            bfr[nt] = *(const bf16x8*)&Bsmem[(waveN * 64 + nt * 16 + l16) * 32 + quad * 8];
#pragma unroll
        for (int mt = 0; mt < 4; ++mt)
#pragma unroll
            for (int nt = 0; nt < 4; ++nt)
                acc[mt][nt] = __builtin_amdgcn_mfma_f32_16x16x32_bf16(af[mt], bfr[nt], acc[mt][nt], 0, 0, 0);
    }
}

// ---------------- fused QKV projection + bias + RoPE + layout ----------------
// z=0: Q -> Qb[bh][t][d] (rope); z=1: K -> Kb[bh][t][d] (rope); z=2: V -> VTb[bh][d][t]
__global__ __launch_bounds__(256) void gemm_qkv_kernel(
    const u16* __restrict__ xb,
    const u16* __restrict__ wqb, const u16* __restrict__ wkb, const u16* __restrict__ wvb,
    const float* __restrict__ bq, const float* __restrict__ bk, const float* __restrict__ bv,
    const float* __restrict__ cosT, const float* __restrict__ sinT,
    u16* __restrict__ Qb, u16* __restrict__ Kb, u16* __restrict__ VTb) {
    __shared__ __align__(16) u16 Asmem[128 * 32];
    __shared__ __align__(16) u16 Bsmem[128 * 32];
    const int z = blockIdx.z;
    const u16* Bw = (z == 0) ? wqb : (z == 1) ? wkb : wvb;
    const float* bias = (z == 0) ? bq : (z == 1) ? bk : bv;

    f32x4 acc[4][4];
#pragma unroll
    for (int mt = 0; mt < 4; ++mt)
#pragma unroll
        for (int nt = 0; nt < 4; ++nt)
            acc[mt][nt] = (f32x4){0.f, 0.f, 0.f, 0.f};

    gemm_tile_core(xb, Bw, blockIdx.x, blockIdx.y, Asmem, Bsmem, acc);

    const int lane = threadIdx.x & 63, wave = threadIdx.x >> 6;
    const int waveM = wave >> 1, waveN = wave & 1;
    const int quad = lane >> 4, l16 = lane & 15;
    const int gm0 = blockIdx.x * 128 + waveM * 64 + quad * 4;
    const int gn0 = blockIdx.y * 128 + waveN * 64 + l16;

    float bvv[4];
#pragma unroll
    for (int nt = 0; nt < 4; ++nt) bvv[nt] = bias[gn0 + nt * 16];
#pragma unroll
    for (int mt = 0; mt < 4; ++mt)
#pragma unroll
        for (int nt = 0; nt < 4; ++nt)
#pragma unroll
            for (int r = 0; r < 4; ++r) acc[mt][nt][r] += bvv[nt];

    if (z < 2) {
        u16* dst = (z == 0) ? Qb : Kb;
#pragma unroll
        for (int mt = 0; mt < 4; ++mt) {
#pragma unroll
            for (int nt = 0; nt < 4; ++nt) {
                int n = gn0 + nt * 16;
                int d = n & 63, h = n >> 6;
#pragma unroll
                for (int r = 0; r < 4; ++r) {
                    int gm = gm0 + mt * 16 + r;
                    int t = gm & (SEQ - 1), b = gm >> 11;
                    float c = cosT[t * HDIM + d], s = sinT[t * HDIM + d];
                    float part = acc[mt][nt ^ 2][r];
                    float rot = (d < 32) ? -part : part;
                    float val = acc[mt][nt][r] * c + rot * s;
                    dst[((b * NHEADS + h) * SEQ + t) * HDIM + d] = f2bf(val);
                }
            }
        }
    } else {
#pragma unroll
        for (int mt = 0; mt < 4; ++mt) {
#pragma unroll
            for (int nt = 0; nt < 4; ++nt) {
                int n = gn0 + nt * 16;
                int d = n & 63, h = n >> 6;
#pragma unroll
                for (int r = 0; r < 4; ++r) {
                    int gm = gm0 + mt * 16 + r;
                    int t = gm & (SEQ - 1), b = gm >> 11;
                    VTb[((b * NHEADS + h) * HDIM + d) * SEQ + t] = f2bf(acc[mt][nt][r]);
                }
            }
        }
    }
}

// ---------------- flash attention ----------------
// grid: x = 16 (q tiles of 128), y = 32 (bh). block = 256 (4 waves, each 32 q rows)
__global__ __launch_bounds__(256) void flash_kernel(
    const u16* __restrict__ Qb, const u16* __restrict__ Kb, const u16* __restrict__ VTb,
    u16* __restrict__ attn) {
    __shared__ __align__(16) u16 Ks[64 * 64];   // [kk][d]
    __shared__ __align__(16) u16 VTs[64 * 64];  // [d][kk]
    __shared__ __align__(16) u16 Ps[4][32 * 64];

    const int tid = threadIdx.x;
    const int wave = tid >> 6, lane = tid & 63;
    const int quad = lane >> 4, l16 = lane & 15;
    const int bh = blockIdx.y;
    const u16* Qh = Qb + (size_t)bh * SEQ * HDIM;
    const u16* Kh = Kb + (size_t)bh * SEQ * HDIM;
    const u16* Vh = VTb + (size_t)bh * HDIM * SEQ;
    const int qbase = blockIdx.x * 128 + wave * 32;
    const float scale = 0.125f; // 1/sqrt(64)

    // Q fragments, kept in registers for the whole kernel
    bf16x8 aq[2][2];
#pragma unroll
    for (int mt = 0; mt < 2; ++mt)
#pragma unroll
        for (int ks = 0; ks < 2; ++ks)
            aq[mt][ks] = *(const bf16x8*)&Qh[(qbase + mt * 16 + l16) * HDIM + ks * 32 + quad * 8];

    f32x4 o[2][4];
    float mst[2][4], lst[2][4];
#pragma unroll
    for (int mt = 0; mt < 2; ++mt)
#pragma unroll
        for (int nt = 0; nt < 4; ++nt) o[mt][nt] = (f32x4){0.f, 0.f, 0.f, 0.f};
#pragma unroll
    for (int mt = 0; mt < 2; ++mt)
#pragma unroll
        for (int r = 0; r < 4; ++r) { mst[mt][r] = -1e30f; lst[mt][r] = 0.f; }

    const int lr = tid >> 3, lc = (tid & 7) * 8;

    for (int kt = 0; kt < SEQ / 64; ++kt) {
        __syncthreads();
        *(int4*)&Ks[lr * 64 + lc] = *(const int4*)&Kh[(kt * 64 + lr) * HDIM + lc];
        *(int4*)&Ks[(lr + 32) * 64 + lc] = *(const int4*)&Kh[(kt * 64 + lr + 32) * HDIM + lc];
        *(int4*)&VTs[lr * 64 + lc] = *(const int4*)&Vh[lr * SEQ + kt * 64 + lc];
        *(int4*)&VTs[(lr + 32) * 64 + lc] = *(const int4*)&Vh[(lr + 32) * SEQ + kt * 64 + lc];
        __syncthreads();

        // S = Q K^T for this tile: [32q x 64k] per wave
        f32x4 sacc[2][4];
#pragma unroll
        for (int mt = 0; mt < 2; ++mt)
#pragma unroll
            for (int nt = 0; nt < 4; ++nt) sacc[mt][nt] = (f32x4){0.f, 0.f, 0.f, 0.f};
#pragma unroll
        for (int ks = 0; ks < 2; ++ks) {
            bf16x8 bk_[4];
#pragma unroll
            for (int nt = 0; nt < 4; ++nt)
                bk_[nt] = *(const bf16x8*)&Ks[(nt * 16 + l16) * 64 + ks * 32 + quad * 8];
#pragma unroll
            for (int mt = 0; mt < 2; ++mt)
#pragma unroll
                for (int nt = 0; nt < 4; ++nt)
                    sacc[mt][nt] = __builtin_amdgcn_mfma_f32_16x16x32_bf16(aq[mt][ks], bk_[nt], sacc[mt][nt], 0, 0, 0);
        }
#pragma unroll
        for (int mt = 0; mt < 2; ++mt)
#pragma unroll
            for (int nt = 0; nt < 4; ++nt)
#pragma unroll
                for (int r = 0; r < 4; ++r) sacc[mt][nt][r] *= scale;

        // online softmax per q-row (rows = quad*4+r within 16-tile)
#pragma unroll
        for (int mt = 0; mt < 2; ++mt) {
            float rowmax[4];
#pragma unroll
            for (int r = 0; r < 4; ++r) {
                float m0 = fmaxf(sacc[mt][0][r], sacc[mt][1][r]);
                float m1 = fmaxf(sacc[mt][2][r], sacc[mt][3][r]);
                rowmax[r] = fmaxf(m0, m1);
            }
#pragma unroll
            for (int off = 1; off < 16; off <<= 1)
#pragma unroll
                for (int r = 0; r < 4; ++r)
                    rowmax[r] = fmaxf(rowmax[r], __shfl_xor(rowmax[r], off, 64));

            float rowsum[4] = {0.f, 0.f, 0.f, 0.f};
#pragma unroll
            for (int r = 0; r < 4; ++r) {
                float mnew = fmaxf(mst[mt][r], rowmax[r]);
                float alpha = __expf(mst[mt][r] - mnew);
                mst[mt][r] = mnew;
                lst[mt][r] *= alpha;
#pragma unroll
                for (int nt = 0; nt < 4; ++nt) o[mt][nt][r] *= alpha;
            }
#pragma unroll
            for (int nt = 0; nt < 4; ++nt) {
#pragma unroll
                for (int r = 0; r < 4; ++r) {
                    float p = __expf(sacc[mt][nt][r] - mst[mt][r]);
                    rowsum[r] += p;
                    Ps[wave][(mt * 16 + quad * 4 + r) * 64 + nt * 16 + l16] = f2bf(p);
                }
            }
#pragma unroll
            for (int off = 1; off < 16; off <<= 1)
#pragma unroll
                for (int r = 0; r < 4; ++r)
                    rowsum[r] += __shfl_xor(rowsum[r], off, 64);
#pragma unroll
            for (int r = 0; r < 4; ++r) lst[mt][r] += rowsum[r];
        }
        __syncthreads(); // make Ps visible (and all lanes' writes complete)

        // O += P V  (A-frag of P from LDS, B-frag from VTs)
#pragma unroll
        for (int ks = 0; ks < 2; ++ks) {
            bf16x8 ap[2], bv_[4];
#pragma unroll
            for (int mt = 0; mt < 2; ++mt)
                ap[mt] = *(const bf16x8*)&Ps[wave][(mt * 16 + l16) * 64 + ks * 32 + quad * 8];
#pragma unroll
            for (int nt = 0; nt < 4; ++nt)
                bv_[nt] = *(const bf16x8*)&VTs[(nt * 16 + l16) * 64 + ks * 32 + quad * 8];
#pragma unroll
            for (int mt = 0; mt < 2; ++mt)
#pragma unroll
                for (int nt = 0; nt < 4; ++nt)
                    o[mt][nt] = __builtin_amdgcn_mfma_f32_16x16x32_bf16(ap[mt], bv_[nt], o[mt][nt], 0, 0, 0);
        }
    }

    // epilogue: normalize, write to attn_out [B*T, 1024] bf16
    const int b = bh >> 4, h = bh & 15;
#pragma unroll
    for (int mt = 0; mt < 2; ++mt) {
#pragma unroll
        for (int nt = 0; nt < 4; ++nt) {
            int d = nt * 16 + l16;
#pragma unroll
            for (int r = 0; r < 4; ++r) {
                int q = qbase + mt * 16 + quad * 4 + r;
                float val = o[mt][nt][r] / lst[mt][r];
                attn[((size_t)(b * SEQ + q)) * D_MODEL + h * HDIM + d] = f2bf(val);
            }
        }
    }
}

// ---------------- output projection ----------------
__global__ __launch_bounds__(256) void gemm_out_kernel(
    const u16* __restrict__ attn, const u16* __restrict__ wob,
    const float* __restrict__ bo, float* __restrict__ dout) {
    __shared__ __align__(16) u16 Asmem[128 * 32];
    __shared__ __align__(16) u16 Bsmem[128 * 32];

    f32x4 acc[4][4];
#pragma unroll
    for (int mt = 0; mt < 4; ++mt)
#pragma unroll
        for (int nt = 0; nt < 4; ++nt) acc[mt][nt] = (f32x4){0.f, 0.f, 0.f, 0.f};

    gemm_tile_core(attn, wob, blockIdx.x, blockIdx.y, Asmem, Bsmem, acc);

    const int lane = threadIdx.x & 63, wave = threadIdx.x >> 6;
    const int waveM = wave >> 1, waveN = wave & 1;
    const int quad = lane >> 4, l16 = lane & 15;
    const int gm0 = blockIdx.x * 128 + waveM * 64 + quad * 4;
    const int gn0 = blockIdx.y * 128 + waveN * 64 + l16;

    float bvv[4];
#pragma unroll
    for (int nt = 0; nt < 4; ++nt) bvv[nt] = bo[gn0 + nt * 16];
#pragma unroll
    for (int mt = 0; mt < 4; ++mt)
#pragma unroll
        for (int nt = 0; nt < 4; ++nt)
#pragma unroll
            for (int r = 0; r < 4; ++r)
                dout[(size_t)(gm0 + mt * 16 + r) * D_MODEL + gn0 + nt * 16] = acc[mt][nt][r] + bvv[nt];
}

// ---------------- launch ----------------
extern "C" void kernel_launch(void* const* d_in, const int* in_sizes, int n_in,
                              void* d_out, int out_size, void* d_ws, size_t ws_size,
                              hipStream_t stream) {
    const float* x  = (const float*)d_in[0];
    const float* Wq = (const float*)d_in[1];
    const float* bq = (const float*)d_in[2];
    const float* Wk = (const float*)d_in[3];
    const float* bk = (const float*)d_in[4];
    const float* Wv = (const float*)d_in[5];
    const float* bv = (const float*)d_in[6];
    const float* Wo = (const float*)d_in[7];
    const float* bo = (const float*)d_in[8];
    float* dout = (float*)d_out;

    char* ws = (char*)d_ws;
    size_t off = 0;
    u16* xb  = (u16*)(ws + off); off += (size_t)BT * D_MODEL * 2;        // 8 MB
    u16* wqb = (u16*)(ws + off); off += (size_t)D_MODEL * D_MODEL * 2;   // 2 MB
    u16* wkb = (u16*)(ws + off); off += (size_t)D_MODEL * D_MODEL * 2;
    u16* wvb = (u16*)(ws + off); off += (size_t)D_MODEL * D_MODEL * 2;
    u16* wob = (u16*)(ws + off); off += (size_t)D_MODEL * D_MODEL * 2;
    u16* Qb  = (u16*)(ws + off); off += (size_t)BT * D_MODEL * 2;        // [32][2048][64]
    u16* Kb  = (u16*)(ws + off); off += (size_t)BT * D_MODEL * 2;
    u16* VTb = (u16*)(ws + off); off += (size_t)BT * D_MODEL * 2;        // [32][64][2048]
    u16* attn = (u16*)(ws + off); off += (size_t)BT * D_MODEL * 2;
    float* cosT = (float*)(ws + off); off += (size_t)SEQ * HDIM * 4;
    float* sinT = (float*)(ws + off); off += (size_t)SEQ * HDIM * 4;

    cast_x_kernel<<<dim3((BT * D_MODEL / 4 + 255) / 256), 256, 0, stream>>>(x, xb, BT * D_MODEL / 4);
    cast_w_kernel<<<dim3(D_MODEL * D_MODEL / 4 / 256, 1, 4), 256, 0, stream>>>(Wq, Wk, Wv, Wo, wqb, wkb, wvb, wob);
    rope_table_kernel<<<dim3(SEQ), dim3(HDIM), 0, stream>>>(cosT, sinT);
    gemm_qkv_kernel<<<dim3(BT / 128, D_MODEL / 128, 3), 256, 0, stream>>>(
        xb, wqb, wkb, wvb, bq, bk, bv, cosT, sinT, Qb, Kb, VTb);
    flash_kernel<<<dim3(SEQ / 128, NBATCH * NHEADS), 256, 0, stream>>>(Qb, Kb, VTb, attn);
    gemm_out_kernel<<<dim3(BT / 128, D_MODEL / 128), 256, 0, stream>>>(attn, wob, bo, dout);
}

// Round 2
// 242.837 us; speedup vs baseline: 1.2765x; 1.2765x over previous
//
#include <hip/hip_runtime.h>
#include <hip/hip_bf16.h>
#include <cstdint>

#define D_MODEL 1024
#define NHEADS 16
#define HDIM 64
#define SEQ 2048
#define NBATCH 2
#define BT (NBATCH * SEQ) /* 4096 */

typedef short bf16x8 __attribute__((ext_vector_type(8)));
typedef float f32x4 __attribute__((ext_vector_type(4)));
typedef unsigned short u16;

__device__ inline u16 f2bf(float f) {  // RNE
    union { float f; unsigned int u; } x;
    x.f = f;
    unsigned int r = (x.u + 0x7fffu + ((x.u >> 16) & 1u)) >> 16;
    return (u16)r;
}

__device__ inline u16 f2bf_fast(float f) {  // half-up, for P >= 0
    union { float f; unsigned int u; } x;
    x.f = f;
    return (u16)((x.u + 0x8000u) >> 16);
}

__device__ inline void async_copy16(const u16* g, u16* l) {
    __builtin_amdgcn_global_load_lds((const __attribute__((address_space(1))) void*)g,
                                     (__attribute__((address_space(3))) void*)l, 16, 0, 0);
}

// ---------------- cast kernels ----------------
__global__ void cast_x_kernel(const float* __restrict__ src, u16* __restrict__ dst, int n4) {
    int i = blockIdx.x * blockDim.x + threadIdx.x;
    if (i >= n4) return;
    float4 v = ((const float4*)src)[i];
    ushort4 o;
    o.x = f2bf(v.x); o.y = f2bf(v.y); o.z = f2bf(v.z); o.w = f2bf(v.w);
    ((ushort4*)dst)[i] = o;
}

__global__ void cast_w_kernel(const float* __restrict__ wq, const float* __restrict__ wk,
                              const float* __restrict__ wv, const float* __restrict__ wo,
                              u16* __restrict__ dq, u16* __restrict__ dk,
                              u16* __restrict__ dv, u16* __restrict__ dow) {
    int z = blockIdx.z;
    const float* s = (z == 0) ? wq : (z == 1) ? wk : (z == 2) ? wv : wo;
    u16* d = (z == 0) ? dq : (z == 1) ? dk : (z == 2) ? dv : dow;
    int i = blockIdx.x * blockDim.x + threadIdx.x;
    float4 v = ((const float4*)s)[i];
    ushort4 o;
    o.x = f2bf(v.x); o.y = f2bf(v.y); o.z = f2bf(v.z); o.w = f2bf(v.w);
    ((ushort4*)d)[i] = o;
}

// ---------------- rope tables ----------------
__global__ void rope_table_kernel(float* __restrict__ cosT, float* __restrict__ sinT) {
    int t = blockIdx.x;
    int d = threadIdx.x; // 0..63
    float invf = expf(-(float)(d & 31) * (9.210340371976184f / 32.0f));
    float ang = (float)t * invf;
    float s, c;
    sincosf(ang, &s, &c);
    cosT[t * HDIM + d] = c;
    sinT[t * HDIM + d] = s;
}

// ---------------- m97-style GEMM core: C[128x128], A[M,K] row-major, Bw[N,K] row-major, K=1024 ----
__device__ inline void gemm_tile_core(const u16* __restrict__ A, const u16* __restrict__ Bw,
                                      int blkM, int blkN,
                                      u16* Asmem, u16* Bsmem, f32x4 acc[4][4]) {
    const int tid = threadIdx.x;
    const int lane = tid & 63;
    const int wave = tid >> 6;
    const int waveM = wave >> 1, waveN = wave & 1;
    const int quad = lane >> 4, l16 = lane & 15;

    // staging map: LDS tile [128][32] u16, linear byte offset = tid*16 (+instr*4096)
    const int srow = tid >> 2;            // 0..63
    const int scol = (tid & 3) << 3;      // u16 col: 0,8,16,24
    const u16* Ag0 = A + (size_t)(blkM * 128 + srow) * D_MODEL + scol;
    const u16* Ag1 = Ag0 + (size_t)64 * D_MODEL;
    const u16* Bg0 = Bw + (size_t)(blkN * 128 + srow) * D_MODEL + scol;
    const u16* Bg1 = Bg0 + (size_t)64 * D_MODEL;
    u16* Al0 = Asmem + srow * 32 + scol;
    u16* Al1 = Al0 + 64 * 32;
    u16* Bl0 = Bsmem + srow * 32 + scol;
    u16* Bl1 = Bl0 + 64 * 32;

    for (int k0 = 0; k0 < D_MODEL; k0 += 32) {
        __syncthreads();
        async_copy16(Ag0 + k0, Al0);
        async_copy16(Ag1 + k0, Al1);
        async_copy16(Bg0 + k0, Bl0);
        async_copy16(Bg1 + k0, Bl1);
        __syncthreads();  // compiler drains vmcnt(0) before barrier
        bf16x8 af[4], bfr[4];
#pragma unroll
        for (int mt = 0; mt < 4; ++mt)
            af[mt] = *(const bf16x8*)&Asmem[(waveM * 64 + mt * 16 + l16) * 32 + quad * 8];
#pragma unroll
        for (int nt = 0; nt < 4; ++nt)
            bfr[nt] = *(const bf16x8*)&Bsmem[(waveN * 64 + nt * 16 + l16) * 32 + quad * 8];
#pragma unroll
        for (int mt = 0; mt < 4; ++mt)
#pragma unroll
            for (int nt = 0; nt < 4; ++nt)
                acc[mt][nt] = __builtin_amdgcn_mfma_f32_16x16x32_bf16(af[mt], bfr[nt], acc[mt][nt], 0, 0, 0);
    }
}

// ---------------- fused QKV projection + bias + RoPE + layout ----------------
// z=0: Q (rope, pre-scaled by 0.125*log2e) -> Qb[bh][t][d]; z=1: K (rope) -> Kb[bh][t][d];
// z=2: V -> VTb[bh][d][t]
#define QSCALE 0.1803368801111204f /* (1/8) * log2(e) */

__global__ __launch_bounds__(256) void gemm_qkv_kernel(
    const u16* __restrict__ xb,
    const u16* __restrict__ wqb, const u16* __restrict__ wkb, const u16* __restrict__ wvb,
    const float* __restrict__ bq, const float* __restrict__ bk, const float* __restrict__ bv,
    const float* __restrict__ cosT, const float* __restrict__ sinT,
    u16* __restrict__ Qb, u16* __restrict__ Kb, u16* __restrict__ VTb) {
    __shared__ __align__(16) u16 Asmem[128 * 32];
    __shared__ __align__(16) u16 Bsmem[128 * 32];
    const int z = blockIdx.z;
    const u16* Bw = (z == 0) ? wqb : (z == 1) ? wkb : wvb;
    const float* bias = (z == 0) ? bq : (z == 1) ? bk : bv;

    f32x4 acc[4][4];
#pragma unroll
    for (int mt = 0; mt < 4; ++mt)
#pragma unroll
        for (int nt = 0; nt < 4; ++nt)
            acc[mt][nt] = (f32x4){0.f, 0.f, 0.f, 0.f};

    gemm_tile_core(xb, Bw, blockIdx.x, blockIdx.y, Asmem, Bsmem, acc);

    const int lane = threadIdx.x & 63, wave = threadIdx.x >> 6;
    const int waveM = wave >> 1, waveN = wave & 1;
    const int quad = lane >> 4, l16 = lane & 15;
    const int gm0 = blockIdx.x * 128 + waveM * 64 + quad * 4;
    const int gn0 = blockIdx.y * 128 + waveN * 64 + l16;

    float bvv[4];
#pragma unroll
    for (int nt = 0; nt < 4; ++nt) bvv[nt] = bias[gn0 + nt * 16];
#pragma unroll
    for (int mt = 0; mt < 4; ++mt)
#pragma unroll
        for (int nt = 0; nt < 4; ++nt)
#pragma unroll
            for (int r = 0; r < 4; ++r) acc[mt][nt][r] += bvv[nt];

    if (z < 2) {
        u16* dst = (z == 0) ? Qb : Kb;
        const float post = (z == 0) ? QSCALE : 1.0f;
#pragma unroll
        for (int mt = 0; mt < 4; ++mt) {
#pragma unroll
            for (int nt = 0; nt < 4; ++nt) {
                int n = gn0 + nt * 16;
                int d = n & 63, h = n >> 6;
#pragma unroll
                for (int r = 0; r < 4; ++r) {
                    int gm = gm0 + mt * 16 + r;
                    int t = gm & (SEQ - 1), b = gm >> 11;
                    float c = cosT[t * HDIM + d], s = sinT[t * HDIM + d];
                    float part = acc[mt][nt ^ 2][r];
                    float rot = (d < 32) ? -part : part;
                    float val = (acc[mt][nt][r] * c + rot * s) * post;
                    dst[((b * NHEADS + h) * SEQ + t) * HDIM + d] = f2bf(val);
                }
            }
        }
    } else {
#pragma unroll
        for (int mt = 0; mt < 4; ++mt) {
#pragma unroll
            for (int nt = 0; nt < 4; ++nt) {
                int n = gn0 + nt * 16;
                int d = n & 63, h = n >> 6;
#pragma unroll
                for (int r = 0; r < 4; ++r) {
                    int gm = gm0 + mt * 16 + r;
                    int t = gm & (SEQ - 1), b = gm >> 11;
                    VTb[((b * NHEADS + h) * HDIM + d) * SEQ + t] = f2bf(acc[mt][nt][r]);
                }
            }
        }
    }
}

// ---------------- flash attention (no-max softmax, deferred row-sum) ----------------
// grid: x = 32 (q tiles of 64), y = 32 (bh). block = 256 (4 waves, each 16 q rows)
#define LPAD 72  /* row stride in u16 for padded LDS tiles */

__global__ __launch_bounds__(256) void flash_kernel(
    const u16* __restrict__ Qb, const u16* __restrict__ Kb, const u16* __restrict__ VTb,
    u16* __restrict__ attn) {
    __shared__ __align__(16) u16 Ks[64 * LPAD];    // [kk][d]
    __shared__ __align__(16) u16 VTs[64 * LPAD];   // [d][kk]
    __shared__ __align__(16) u16 Ps[4][16 * LPAD]; // per-wave [q][kk]

    const int tid = threadIdx.x;
    const int wave = tid >> 6, lane = tid & 63;
    const int quad = lane >> 4, l16 = lane & 15;
    const int bh = blockIdx.y;
    const u16* Qh = Qb + (size_t)bh * SEQ * HDIM;
    const u16* Kh = Kb + (size_t)bh * SEQ * HDIM;
    const u16* Vh = VTb + (size_t)bh * HDIM * SEQ;
    const int qbase = blockIdx.x * 64 + wave * 16;

    // Q fragments for this wave's 16 rows (Q pre-scaled by 0.125*log2e)
    bf16x8 aq[2];
#pragma unroll
    for (int ks = 0; ks < 2; ++ks)
        aq[ks] = *(const bf16x8*)&Qh[(qbase + l16) * HDIM + ks * 32 + quad * 8];

    f32x4 o[4];
    float lsum[4] = {0.f, 0.f, 0.f, 0.f};
#pragma unroll
    for (int nt = 0; nt < 4; ++nt) o[nt] = (f32x4){0.f, 0.f, 0.f, 0.f};

    const int lr = tid >> 3, lc = (tid & 7) * 8;

    for (int kt = 0; kt < SEQ / 64; ++kt) {
        __syncthreads();
        *(int4*)&Ks[lr * LPAD + lc] = *(const int4*)&Kh[(kt * 64 + lr) * HDIM + lc];
        *(int4*)&Ks[(lr + 32) * LPAD + lc] = *(const int4*)&Kh[(kt * 64 + lr + 32) * HDIM + lc];
        *(int4*)&VTs[lr * LPAD + lc] = *(const int4*)&Vh[lr * SEQ + kt * 64 + lc];
        *(int4*)&VTs[(lr + 32) * LPAD + lc] = *(const int4*)&Vh[(lr + 32) * SEQ + kt * 64 + lc];
        __syncthreads();

        // S = Q K^T : [16q x 64k] per wave (already in exp2 units)
        f32x4 sacc[4];
#pragma unroll
        for (int nt = 0; nt < 4; ++nt) sacc[nt] = (f32x4){0.f, 0.f, 0.f, 0.f};
#pragma unroll
        for (int ks = 0; ks < 2; ++ks) {
            bf16x8 bk_[4];
#pragma unroll
            for (int nt = 0; nt < 4; ++nt)
                bk_[nt] = *(const bf16x8*)&Ks[(nt * 16 + l16) * LPAD + ks * 32 + quad * 8];
#pragma unroll
            for (int nt = 0; nt < 4; ++nt)
                sacc[nt] = __builtin_amdgcn_mfma_f32_16x16x32_bf16(aq[ks], bk_[nt], sacc[nt], 0, 0, 0);
        }

        // p = exp2(s) (no max subtraction; clamp as inf-insurance), accumulate row sums
#pragma unroll
        for (int nt = 0; nt < 4; ++nt) {
#pragma unroll
            for (int r = 0; r < 4; ++r) {
                float p = __builtin_amdgcn_exp2f(fminf(sacc[nt][r], 60.0f));
                lsum[r] += p;
                Ps[wave][(quad * 4 + r) * LPAD + nt * 16 + l16] = f2bf_fast(p);
            }
        }
        // no barrier: Ps is per-wave; lgkmcnt ordering suffices

        // O += P V
#pragma unroll
        for (int ks = 0; ks < 2; ++ks) {
            bf16x8 ap, bv_[4];
            ap = *(const bf16x8*)&Ps[wave][l16 * LPAD + ks * 32 + quad * 8];
#pragma unroll
            for (int nt = 0; nt < 4; ++nt)
                bv_[nt] = *(const bf16x8*)&VTs[(nt * 16 + l16) * LPAD + ks * 32 + quad * 8];
#pragma unroll
            for (int nt = 0; nt < 4; ++nt)
                o[nt] = __builtin_amdgcn_mfma_f32_16x16x32_bf16(ap, bv_[nt], o[nt], 0, 0, 0);
        }
    }

    // deferred row-sum reduction across the 16 lanes of each quad
#pragma unroll
    for (int off = 1; off < 16; off <<= 1)
#pragma unroll
        for (int r = 0; r < 4; ++r)
            lsum[r] += __shfl_xor(lsum[r], off, 64);

    // epilogue: normalize, write attn [B*T, 1024] bf16
    const int b = bh >> 4, h = bh & 15;
    float rinv[4];
#pragma unroll
    for (int r = 0; r < 4; ++r) rinv[r] = 1.0f / lsum[r];
#pragma unroll
    for (int nt = 0; nt < 4; ++nt) {
        int d = nt * 16 + l16;
#pragma unroll
        for (int r = 0; r < 4; ++r) {
            int q = qbase + quad * 4 + r;
            attn[((size_t)(b * SEQ + q)) * D_MODEL + h * HDIM + d] = f2bf(o[nt][r] * rinv[r]);
        }
    }
}

// ---------------- output projection ----------------
__global__ __launch_bounds__(256) void gemm_out_kernel(
    const u16* __restrict__ attn, const u16* __restrict__ wob,
    const float* __restrict__ bo, float* __restrict__ dout) {
    __shared__ __align__(16) u16 Asmem[128 * 32];
    __shared__ __align__(16) u16 Bsmem[128 * 32];

    f32x4 acc[4][4];
#pragma unroll
    for (int mt = 0; mt < 4; ++mt)
#pragma unroll
        for (int nt = 0; nt < 4; ++nt) acc[mt][nt] = (f32x4){0.f, 0.f, 0.f, 0.f};

    gemm_tile_core(attn, wob, blockIdx.x, blockIdx.y, Asmem, Bsmem, acc);

    const int lane = threadIdx.x & 63, wave = threadIdx.x >> 6;
    const int waveM = wave >> 1, waveN = wave & 1;
    const int quad = lane >> 4, l16 = lane & 15;
    const int gm0 = blockIdx.x * 128 + waveM * 64 + quad * 4;
    const int gn0 = blockIdx.y * 128 + waveN * 64 + l16;

    float bvv[4];
#pragma unroll
    for (int nt = 0; nt < 4; ++nt) bvv[nt] = bo[gn0 + nt * 16];
#pragma unroll
    for (int mt = 0; mt < 4; ++mt)
#pragma unroll
        for (int nt = 0; nt < 4; ++nt)
#pragma unroll
            for (int r = 0; r < 4; ++r)
                dout[(size_t)(gm0 + mt * 16 + r) * D_MODEL + gn0 + nt * 16] = acc[mt][nt][r] + bvv[nt];
}

// ---------------- launch ----------------
extern "C" void kernel_launch(void* const* d_in, const int* in_sizes, int n_in,
                              void* d_out, int out_size, void* d_ws, size_t ws_size,
                              hipStream_t stream) {
    const float* x  = (const float*)d_in[0];
    const float* Wq = (const float*)d_in[1];
    const float* bq = (const float*)d_in[2];
    const float* Wk = (const float*)d_in[3];
    const float* bk = (const float*)d_in[4];
    const float* Wv = (const float*)d_in[5];
    const float* bv = (const float*)d_in[6];
    const float* Wo = (const float*)d_in[7];
    const float* bo = (const float*)d_in[8];
    float* dout = (float*)d_out;

    char* ws = (char*)d_ws;
    size_t off = 0;
    u16* xb  = (u16*)(ws + off); off += (size_t)BT * D_MODEL * 2;
    u16* wqb = (u16*)(ws + off); off += (size_t)D_MODEL * D_MODEL * 2;
    u16* wkb = (u16*)(ws + off); off += (size_t)D_MODEL * D_MODEL * 2;
    u16* wvb = (u16*)(ws + off); off += (size_t)D_MODEL * D_MODEL * 2;
    u16* wob = (u16*)(ws + off); off += (size_t)D_MODEL * D_MODEL * 2;
    u16* Qb  = (u16*)(ws + off); off += (size_t)BT * D_MODEL * 2;
    u16* Kb  = (u16*)(ws + off); off += (size_t)BT * D_MODEL * 2;
    u16* VTb = (u16*)(ws + off); off += (size_t)BT * D_MODEL * 2;
    u16* attn = (u16*)(ws + off); off += (size_t)BT * D_MODEL * 2;
    float* cosT = (float*)(ws + off); off += (size_t)SEQ * HDIM * 4;
    float* sinT = (float*)(ws + off); off += (size_t)SEQ * HDIM * 4;

    cast_x_kernel<<<dim3((BT * D_MODEL / 4 + 255) / 256), 256, 0, stream>>>(x, xb, BT * D_MODEL / 4);
    cast_w_kernel<<<dim3(D_MODEL * D_MODEL / 4 / 256, 1, 4), 256, 0, stream>>>(Wq, Wk, Wv, Wo, wqb, wkb, wvb, wob);
    rope_table_kernel<<<dim3(SEQ), dim3(HDIM), 0, stream>>>(cosT, sinT);
    gemm_qkv_kernel<<<dim3(BT / 128, D_MODEL / 128, 3), 256, 0, stream>>>(
        xb, wqb, wkb, wvb, bq, bk, bv, cosT, sinT, Qb, Kb, VTb);
    flash_kernel<<<dim3(SEQ / 64, NBATCH * NHEADS), 256, 0, stream>>>(Qb, Kb, VTb, attn);
    gemm_out_kernel<<<dim3(BT / 128, D_MODEL / 128), 256, 0, stream>>>(attn, wob, bo, dout);
}

// Round 3
// 229.628 us; speedup vs baseline: 1.3499x; 1.0575x over previous
//
#include <hip/hip_runtime.h>
#include <hip/hip_bf16.h>
#include <cstdint>

#define D_MODEL 1024
#define NHEADS 16
#define HDIM 64
#define SEQ 2048
#define NBATCH 2
#define BT (NBATCH * SEQ) /* 4096 */

typedef short bf16x8 __attribute__((ext_vector_type(8)));
typedef float f32x4 __attribute__((ext_vector_type(4)));
typedef unsigned short u16;
typedef unsigned int u32;

__device__ inline u16 f2bf(float f) {  // RNE
    union { float f; u32 u; } x;
    x.f = f;
    u32 r = (x.u + 0x7fffu + ((x.u >> 16) & 1u)) >> 16;
    return (u16)r;
}

__device__ inline u32 pack2bf(float a, float b) {  // lo=bf16(a), hi=bf16(b), half-up
    union { float f; u32 u; } x, y;
    x.f = a; y.f = b;
    return ((x.u + 0x8000u) >> 16) | ((y.u + 0x8000u) & 0xffff0000u);
}

__device__ inline void async_copy16(const u16* g, u16* l) {
    __builtin_amdgcn_global_load_lds((const __attribute__((address_space(1))) void*)g,
                                     (__attribute__((address_space(3))) void*)l, 16, 0, 0);
}

// ---------------- prep: casts + rope tables, one launch ----------------
#define X4 (BT * D_MODEL / 4)        /* 1048576 = 2^20 */
#define W4 (D_MODEL * D_MODEL / 4)   /* 262144  = 2^18 */
#define ROPE_N (SEQ * 32)            /* 65536 */

__global__ void prep_kernel(const float* __restrict__ x,
                            const float* __restrict__ wq, const float* __restrict__ wk,
                            const float* __restrict__ wv, const float* __restrict__ wo,
                            u16* __restrict__ xb,
                            u16* __restrict__ dq, u16* __restrict__ dk,
                            u16* __restrict__ dv, u16* __restrict__ dow,
                            float* __restrict__ cosT, float* __restrict__ sinT) {
    int idx = blockIdx.x * blockDim.x + threadIdx.x;
    if (idx < X4) {
        float4 v = ((const float4*)x)[idx];
        ushort4 o;
        o.x = f2bf(v.x); o.y = f2bf(v.y); o.z = f2bf(v.z); o.w = f2bf(v.w);
        ((ushort4*)xb)[idx] = o;
    } else if (idx < X4 + 4 * W4) {
        int j = idx - X4;
        int w = j >> 18, i = j & (W4 - 1);
        const float* s = (w == 0) ? wq : (w == 1) ? wk : (w == 2) ? wv : wo;
        u16* d = (w == 0) ? dq : (w == 1) ? dk : (w == 2) ? dv : dow;
        float4 v = ((const float4*)s)[i];
        ushort4 o;
        o.x = f2bf(v.x); o.y = f2bf(v.y); o.z = f2bf(v.z); o.w = f2bf(v.w);
        ((ushort4*)d)[i] = o;
    } else {
        int j = idx - (X4 + 4 * W4);
        if (j < ROPE_N) {
            int t = j >> 5, dd = j & 31;
            float invf = exp2f(-(float)dd * (13.287712379549449f / 32.0f));
            float ang = (float)t * invf;
            float s, c;
            sincosf(ang, &s, &c);
            cosT[t * HDIM + dd] = c;      cosT[t * HDIM + dd + 32] = c;
            sinT[t * HDIM + dd] = s;      sinT[t * HDIM + dd + 32] = s;
        }
    }
}

// ---------------- m97-style GEMM core ----------------
__device__ inline void gemm_tile_core(const u16* __restrict__ A, const u16* __restrict__ Bw,
                                      int blkM, int blkN,
                                      u16* Asmem, u16* Bsmem, f32x4 acc[4][4]) {
    const int tid = threadIdx.x;
    const int lane = tid & 63;
    const int wave = tid >> 6;
    const int waveM = wave >> 1, waveN = wave & 1;
    const int quad = lane >> 4, l16 = lane & 15;

    const int srow = tid >> 2;
    const int scol = (tid & 3) << 3;
    const u16* Ag0 = A + (size_t)(blkM * 128 + srow) * D_MODEL + scol;
    const u16* Ag1 = Ag0 + (size_t)64 * D_MODEL;
    const u16* Bg0 = Bw + (size_t)(blkN * 128 + srow) * D_MODEL + scol;
    const u16* Bg1 = Bg0 + (size_t)64 * D_MODEL;
    u16* Al0 = Asmem + srow * 32 + scol;
    u16* Al1 = Al0 + 64 * 32;
    u16* Bl0 = Bsmem + srow * 32 + scol;
    u16* Bl1 = Bl0 + 64 * 32;

    for (int k0 = 0; k0 < D_MODEL; k0 += 32) {
        __syncthreads();
        async_copy16(Ag0 + k0, Al0);
        async_copy16(Ag1 + k0, Al1);
        async_copy16(Bg0 + k0, Bl0);
        async_copy16(Bg1 + k0, Bl1);
        __syncthreads();
        bf16x8 af[4], bfr[4];
#pragma unroll
        for (int mt = 0; mt < 4; ++mt)
            af[mt] = *(const bf16x8*)&Asmem[(waveM * 64 + mt * 16 + l16) * 32 + quad * 8];
#pragma unroll
        for (int nt = 0; nt < 4; ++nt)
            bfr[nt] = *(const bf16x8*)&Bsmem[(waveN * 64 + nt * 16 + l16) * 32 + quad * 8];
#pragma unroll
        for (int mt = 0; mt < 4; ++mt)
#pragma unroll
            for (int nt = 0; nt < 4; ++nt)
                acc[mt][nt] = __builtin_amdgcn_mfma_f32_16x16x32_bf16(af[mt], bfr[nt], acc[mt][nt], 0, 0, 0);
    }
}

// ---------------- fused QKV projection + bias + RoPE + layout ----------------
#define QSCALE 0.1803368801111204f /* (1/8) * log2(e) */

__global__ __launch_bounds__(256) void gemm_qkv_kernel(
    const u16* __restrict__ xb,
    const u16* __restrict__ wqb, const u16* __restrict__ wkb, const u16* __restrict__ wvb,
    const float* __restrict__ bq, const float* __restrict__ bk, const float* __restrict__ bv,
    const float* __restrict__ cosT, const float* __restrict__ sinT,
    u16* __restrict__ Qb, u16* __restrict__ Kb, u16* __restrict__ VTb) {
    __shared__ __align__(16) u16 Asmem[128 * 32];
    __shared__ __align__(16) u16 Bsmem[128 * 32];
    const int z = blockIdx.z;
    const u16* Bw = (z == 0) ? wqb : (z == 1) ? wkb : wvb;
    const float* bias = (z == 0) ? bq : (z == 1) ? bk : bv;

    f32x4 acc[4][4];
#pragma unroll
    for (int mt = 0; mt < 4; ++mt)
#pragma unroll
        for (int nt = 0; nt < 4; ++nt)
            acc[mt][nt] = (f32x4){0.f, 0.f, 0.f, 0.f};

    gemm_tile_core(xb, Bw, blockIdx.x, blockIdx.y, Asmem, Bsmem, acc);

    const int lane = threadIdx.x & 63, wave = threadIdx.x >> 6;
    const int waveM = wave >> 1, waveN = wave & 1;
    const int quad = lane >> 4, l16 = lane & 15;
    const int gm0 = blockIdx.x * 128 + waveM * 64 + quad * 4;
    const int gn0 = blockIdx.y * 128 + waveN * 64 + l16;

    float bvv[4];
#pragma unroll
    for (int nt = 0; nt < 4; ++nt) bvv[nt] = bias[gn0 + nt * 16];
#pragma unroll
    for (int mt = 0; mt < 4; ++mt)
#pragma unroll
        for (int nt = 0; nt < 4; ++nt)
#pragma unroll
            for (int r = 0; r < 4; ++r) acc[mt][nt][r] += bvv[nt];

    if (z < 2) {
        u16* dst = (z == 0) ? Qb : Kb;
        const float post = (z == 0) ? QSCALE : 1.0f;
#pragma unroll
        for (int mt = 0; mt < 4; ++mt) {
#pragma unroll
            for (int nt = 0; nt < 4; ++nt) {
                int n = gn0 + nt * 16;
                int d = n & 63, h = n >> 6;
#pragma unroll
                for (int r = 0; r < 4; ++r) {
                    int gm = gm0 + mt * 16 + r;
                    int t = gm & (SEQ - 1), b = gm >> 11;
                    float c = cosT[t * HDIM + d], s = sinT[t * HDIM + d];
                    float part = acc[mt][nt ^ 2][r];
                    float rot = (d < 32) ? -part : part;
                    float val = (acc[mt][nt][r] * c + rot * s) * post;
                    dst[((b * NHEADS + h) * SEQ + t) * HDIM + d] = f2bf(val);
                }
            }
        }
    } else {
        // V -> VTb[bh][d][t]; 4 consecutive t per lane -> packed b64 stores
#pragma unroll
        for (int mt = 0; mt < 4; ++mt) {
            int gm = gm0 + mt * 16;
            int t0 = gm & (SEQ - 1), b = gm >> 11;
#pragma unroll
            for (int nt = 0; nt < 4; ++nt) {
                int n = gn0 + nt * 16;
                int d = n & 63, h = n >> 6;
                uint2 w;
                w.x = pack2bf(acc[mt][nt][0], acc[mt][nt][1]);
                w.y = pack2bf(acc[mt][nt][2], acc[mt][nt][3]);
                *(uint2*)&VTb[((size_t)(b * NHEADS + h) * HDIM + d) * SEQ + t0] = w;
            }
        }
    }
}

// ---------------- flash attention: S^T = K Q^T trick, no-max softmax ----------------
// grid: x = 16 (q tiles of 128), y = 32 (bh). block = 256 = 4 waves, each wave owns 32 q rows.
#define LPAD 72  /* row stride in u16 */

__global__ __launch_bounds__(256) void flash_kernel(
    const u16* __restrict__ Qb, const u16* __restrict__ Kb, const u16* __restrict__ VTb,
    u16* __restrict__ attn) {
    __shared__ __align__(16) u16 Ks[64 * LPAD];    // [kk][d]
    __shared__ __align__(16) u16 VTs[64 * LPAD];   // [d][kk]
    __shared__ __align__(16) u16 Ps[4][32 * LPAD]; // per-wave [q][kk]

    const int tid = threadIdx.x;
    const int wave = tid >> 6, lane = tid & 63;
    const int quad = lane >> 4, l16 = lane & 15;
    const int bh = blockIdx.y;
    const u16* Qh = Qb + (size_t)bh * SEQ * HDIM;
    const u16* Kh = Kb + (size_t)bh * SEQ * HDIM;
    const u16* Vh = VTb + (size_t)bh * HDIM * SEQ;
    const int qblk = blockIdx.x * 128 + wave * 32;
    u16* Pw = (u16*)Ps[wave];

    // Q B-frags (Q pre-scaled by 0.125*log2e): aq[nt2][ks]
    bf16x8 aq[2][2];
#pragma unroll
    for (int nt2 = 0; nt2 < 2; ++nt2)
#pragma unroll
        for (int ks = 0; ks < 2; ++ks)
            aq[nt2][ks] = *(const bf16x8*)&Qh[(qblk + nt2 * 16 + l16) * HDIM + ks * 32 + quad * 8];

    f32x4 o[2][4];
    float lsum[2] = {0.f, 0.f};
#pragma unroll
    for (int mt2 = 0; mt2 < 2; ++mt2)
#pragma unroll
        for (int nt = 0; nt < 4; ++nt) o[mt2][nt] = (f32x4){0.f, 0.f, 0.f, 0.f};

    const int lr = tid >> 2;         // 0..63
    const int lc = (tid & 3) * 16;   // u16 col: 0,16,32,48

    for (int kt = 0; kt < SEQ / 64; ++kt) {
        __syncthreads();
        *(int4*)&Ks[lr * LPAD + lc] = *(const int4*)&Kh[(kt * 64 + lr) * HDIM + lc];
        *(int4*)&Ks[lr * LPAD + lc + 8] = *(const int4*)&Kh[(kt * 64 + lr) * HDIM + lc + 8];
        *(int4*)&VTs[lr * LPAD + lc] = *(const int4*)&Vh[lr * SEQ + kt * 64 + lc];
        *(int4*)&VTs[lr * LPAD + lc + 8] = *(const int4*)&Vh[lr * SEQ + kt * 64 + lc + 8];
        __syncthreads();

        // S^T[kk][q] = K·Q^T : per wave 64kk x 32q. C/D: col(l16)=q, row(quad*4+r)=kk
        f32x4 sacc[4][2];
#pragma unroll
        for (int mt = 0; mt < 4; ++mt)
#pragma unroll
            for (int nt2 = 0; nt2 < 2; ++nt2) sacc[mt][nt2] = (f32x4){0.f, 0.f, 0.f, 0.f};
#pragma unroll
        for (int ks = 0; ks < 2; ++ks) {
            bf16x8 kf[4];
#pragma unroll
            for (int mt = 0; mt < 4; ++mt)
                kf[mt] = *(const bf16x8*)&Ks[(mt * 16 + l16) * LPAD + ks * 32 + quad * 8];
#pragma unroll
            for (int mt = 0; mt < 4; ++mt)
#pragma unroll
                for (int nt2 = 0; nt2 < 2; ++nt2)
                    sacc[mt][nt2] = __builtin_amdgcn_mfma_f32_16x16x32_bf16(kf[mt], aq[nt2][ks], sacc[mt][nt2], 0, 0, 0);
        }

        // P = exp2(S) (Q pre-scaled). Lane holds 4 contiguous kk per (mt,nt2) -> b64 write.
#pragma unroll
        for (int mt = 0; mt < 4; ++mt) {
#pragma unroll
            for (int nt2 = 0; nt2 < 2; ++nt2) {
                float p0 = __builtin_amdgcn_exp2f(fminf(sacc[mt][nt2][0], 60.0f));
                float p1 = __builtin_amdgcn_exp2f(fminf(sacc[mt][nt2][1], 60.0f));
                float p2 = __builtin_amdgcn_exp2f(fminf(sacc[mt][nt2][2], 60.0f));
                float p3 = __builtin_amdgcn_exp2f(fminf(sacc[mt][nt2][3], 60.0f));
                lsum[nt2] += (p0 + p1) + (p2 + p3);
                uint2 w;
                w.x = pack2bf(p0, p1);
                w.y = pack2bf(p2, p3);
                *(uint2*)&Pw[(nt2 * 16 + l16) * LPAD + mt * 16 + quad * 4] = w;
            }
        }
        // no barrier: Ps slice is private to this wave; DS ops are wave-ordered

        // O += P·V : A=P[q][kk] frags, B=V[d][kk] frags
#pragma unroll
        for (int ks = 0; ks < 2; ++ks) {
            bf16x8 pf[2], vf[4];
#pragma unroll
            for (int mt2 = 0; mt2 < 2; ++mt2)
                pf[mt2] = *(const bf16x8*)&Pw[(mt2 * 16 + l16) * LPAD + ks * 32 + quad * 8];
#pragma unroll
            for (int nt = 0; nt < 4; ++nt)
                vf[nt] = *(const bf16x8*)&VTs[(nt * 16 + l16) * LPAD + ks * 32 + quad * 8];
#pragma unroll
            for (int mt2 = 0; mt2 < 2; ++mt2)
#pragma unroll
                for (int nt = 0; nt < 4; ++nt)
                    o[mt2][nt] = __builtin_amdgcn_mfma_f32_16x16x32_bf16(pf[mt2], vf[nt], o[mt2][nt], 0, 0, 0);
        }
    }

    // complete row sums: reduce over the 4 quads (lanes l16, +16, +32, +48 hold disjoint kk)
#pragma unroll
    for (int nt2 = 0; nt2 < 2; ++nt2) {
        lsum[nt2] += __shfl_xor(lsum[nt2], 16, 64);
        lsum[nt2] += __shfl_xor(lsum[nt2], 32, 64);
    }
    // redistribute: O lane needs 1/lsum for q = mt2*16 + quad*4 + r (held at lane l16'=quad*4+r)
    float rinv[2][4];
#pragma unroll
    for (int mt2 = 0; mt2 < 2; ++mt2)
#pragma unroll
        for (int r = 0; r < 4; ++r)
            rinv[mt2][r] = 1.0f / __shfl(lsum[mt2], quad * 4 + r, 64);

    // epilogue: write attn [B*T, 1024] bf16. O C/D: col(l16)=d, row(quad*4+r)=q
    const int b = bh >> 4, h = bh & 15;
#pragma unroll
    for (int mt2 = 0; mt2 < 2; ++mt2) {
#pragma unroll
        for (int nt = 0; nt < 4; ++nt) {
            int d = nt * 16 + l16;
#pragma unroll
            for (int r = 0; r < 4; ++r) {
                int q = qblk + mt2 * 16 + quad * 4 + r;
                attn[((size_t)(b * SEQ + q)) * D_MODEL + h * HDIM + d] = f2bf(o[mt2][nt][r] * rinv[mt2][r]);
            }
        }
    }
}

// ---------------- output projection ----------------
__global__ __launch_bounds__(256) void gemm_out_kernel(
    const u16* __restrict__ attn, const u16* __restrict__ wob,
    const float* __restrict__ bo, float* __restrict__ dout) {
    __shared__ __align__(16) u16 Asmem[128 * 32];
    __shared__ __align__(16) u16 Bsmem[128 * 32];

    f32x4 acc[4][4];
#pragma unroll
    for (int mt = 0; mt < 4; ++mt)
#pragma unroll
        for (int nt = 0; nt < 4; ++nt) acc[mt][nt] = (f32x4){0.f, 0.f, 0.f, 0.f};

    gemm_tile_core(attn, wob, blockIdx.x, blockIdx.y, Asmem, Bsmem, acc);

    const int lane = threadIdx.x & 63, wave = threadIdx.x >> 6;
    const int waveM = wave >> 1, waveN = wave & 1;
    const int quad = lane >> 4, l16 = lane & 15;
    const int gm0 = blockIdx.x * 128 + waveM * 64 + quad * 4;
    const int gn0 = blockIdx.y * 128 + waveN * 64 + l16;

    float bvv[4];
#pragma unroll
    for (int nt = 0; nt < 4; ++nt) bvv[nt] = bo[gn0 + nt * 16];
#pragma unroll
    for (int mt = 0; mt < 4; ++mt)
#pragma unroll
        for (int nt = 0; nt < 4; ++nt)
#pragma unroll
            for (int r = 0; r < 4; ++r)
                dout[(size_t)(gm0 + mt * 16 + r) * D_MODEL + gn0 + nt * 16] = acc[mt][nt][r] + bvv[nt];
}

// ---------------- launch ----------------
extern "C" void kernel_launch(void* const* d_in, const int* in_sizes, int n_in,
                              void* d_out, int out_size, void* d_ws, size_t ws_size,
                              hipStream_t stream) {
    const float* x  = (const float*)d_in[0];
    const float* Wq = (const float*)d_in[1];
    const float* bq = (const float*)d_in[2];
    const float* Wk = (const float*)d_in[3];
    const float* bk = (const float*)d_in[4];
    const float* Wv = (const float*)d_in[5];
    const float* bv = (const float*)d_in[6];
    const float* Wo = (const float*)d_in[7];
    const float* bo = (const float*)d_in[8];
    float* dout = (float*)d_out;

    char* ws = (char*)d_ws;
    size_t off = 0;
    u16* xb  = (u16*)(ws + off); off += (size_t)BT * D_MODEL * 2;
    u16* wqb = (u16*)(ws + off); off += (size_t)D_MODEL * D_MODEL * 2;
    u16* wkb = (u16*)(ws + off); off += (size_t)D_MODEL * D_MODEL * 2;
    u16* wvb = (u16*)(ws + off); off += (size_t)D_MODEL * D_MODEL * 2;
    u16* wob = (u16*)(ws + off); off += (size_t)D_MODEL * D_MODEL * 2;
    u16* Qb  = (u16*)(ws + off); off += (size_t)BT * D_MODEL * 2;
    u16* Kb  = (u16*)(ws + off); off += (size_t)BT * D_MODEL * 2;
    u16* VTb = (u16*)(ws + off); off += (size_t)BT * D_MODEL * 2;
    u16* attn = (u16*)(ws + off); off += (size_t)BT * D_MODEL * 2;
    float* cosT = (float*)(ws + off); off += (size_t)SEQ * HDIM * 4;
    float* sinT = (float*)(ws + off); off += (size_t)SEQ * HDIM * 4;

    const int prepN = X4 + 4 * W4 + ROPE_N;
    prep_kernel<<<dim3((prepN + 255) / 256), 256, 0, stream>>>(
        x, Wq, Wk, Wv, Wo, xb, wqb, wkb, wvb, wob, cosT, sinT);
    gemm_qkv_kernel<<<dim3(BT / 128, D_MODEL / 128, 3), 256, 0, stream>>>(
        xb, wqb, wkb, wvb, bq, bk, bv, cosT, sinT, Qb, Kb, VTb);
    flash_kernel<<<dim3(SEQ / 128, NBATCH * NHEADS), 256, 0, stream>>>(Qb, Kb, VTb, attn);
    gemm_out_kernel<<<dim3(BT / 128, D_MODEL / 128), 256, 0, stream>>>(attn, wob, bo, dout);
}